// Round 10
// baseline (860.633 us; speedup 1.0000x reference)
//
#include <hip/hip_runtime.h>
#include <hip/hip_bf16.h>

// Problem constants
#define NND 50000      // nodes
#define NED 800000     // edges (without self-loops)
#define INC 10
#define HID 96
#define OUTC 48
#define NOUT (NND*OUTC)
#define MTILES 3125    // 50000 / 16
#define SPAN 512       // dest-window nodes per build block
#define CBLK 98        // 98*512 = 50176 >= NND
#define CAPB 8960      // records per block region; Poisson(8192)+8.5 sigma

typedef __hip_bfloat16 bf16;
typedef __attribute__((ext_vector_type(8))) short short8;
typedef __attribute__((ext_vector_type(4))) float f32x4;

// ---- workspace layout ----
// header ints: [0..1] flags (written by k_prep block 0). 256B reserved.
// F floats (from d_ws+256):
#define XF_O   0L                 // 500000  (x: N x 10, fp32)
#define W1F_O  500000L            // 960   (W1 then b1 contiguous: 1056)
#define B1F_O  500960L            // 96
#define WMF_O  501056L            // 4608  (fp32 copy; heads use bf16 wct)
#define BMF_O  505664L            // 48
#define WLF_O  505712L            // 4608
#define BLF_O  510320L            // 48
#define DIS_O  510368L            // 50000 (rsqrt(deg+1), written by k_count)
#define FLOATS_TOT 560368L
// then: h [NND*96] bf16, wct [96*96] bf16, v [NND*96] bf16
// then ints: cnt[50000], start[50000], pk[800000], edges[CBLK*CAPB] int2

__device__ __forceinline__ float b2f(bf16 v) { return __bfloat162float(v); }
__device__ __forceinline__ float bfLo(unsigned int p) { return __uint_as_float(p << 16); }
__device__ __forceinline__ float bfHi(unsigned int p) { return __uint_as_float(p & 0xffff0000u); }
__device__ __forceinline__ unsigned short f2bu(float v) {
    return __bfloat16_as_ushort(__float2bfloat16(v));
}

// K1: block-local dtype sniff + convert-to-fp32 + bf16 transposed head-weight
//     build + edge pack (row | col<<16). NO global atomics.
#define CVT_TOT 510368
#define PACK_THREADS 200000
__global__ __launch_bounds__(256) void k_prep(const void* x, const void* w1, const void* b1,
                                              const void* wm, const void* bm,
                                              const void* wl, const void* bl,
                                              const int* ei, int* flags,
                                              float* F, unsigned short* wct,
                                              unsigned int* pk) {
    __shared__ int s_oddnz, s_big;
    if (threadIdx.x == 0) { s_oddnz = 0; s_big = 0; }
    __syncthreads();
    {
        int t = threadIdx.x;
        if (t < 128) {
            if (ei[2 * t + 1] != 0) atomicOr(&s_oddnz, 1);
        }
        const unsigned short* xs = (const unsigned short*)x;
        unsigned short u = xs[t * 8];
        float f = __uint_as_float(((unsigned int)u) << 16);
        int big = !(fabsf(f) < 64.0f);
        unsigned short u2 = xs[t * 8 + 5];
        float f2 = __uint_as_float(((unsigned int)u2) << 16);
        big |= !(fabsf(f2) < 64.0f);
        if (big) atomicOr(&s_big, 1);
    }
    __syncthreads();
    int iw = (s_oddnz == 0) ? 1 : 0;   // 1 = int64 edge_index
    int ff = s_big ? 1 : 0;            // 1 = fp32 floats
    if (blockIdx.x == 0 && threadIdx.x == 0) { flags[0] = iw; flags[1] = ff; }

    int idx = blockIdx.x * 256 + threadIdx.x;
    if (idx < CVT_TOT) {
        const void* src; long off;
        if      (idx < 500000) { src = x;  off = idx; }
        else if (idx < 500960) { src = w1; off = idx - 500000; }
        else if (idx < 501056) { src = b1; off = idx - 500960; }
        else if (idx < 505664) { src = wm; off = idx - 501056; }
        else if (idx < 505712) { src = bm; off = idx - 505664; }
        else if (idx < 510320) { src = wl; off = idx - 505712; }
        else                   { src = bl; off = idx - 510320; }
        float v = ff ? ((const float*)src)[off] : b2f(((const bf16*)src)[off]);
        F[idx] = v;
        if (idx >= 501056 && idx < 505664) {          // W_mu[k][j] -> wct[j][k]
            long rel = idx - 501056;
            wct[(rel % OUTC) * (long)HID + rel / OUTC] = f2bu(v);
        } else if (idx >= 505712 && idx < 510320) {   // W_ls[k][j] -> wct[48+j][k]
            long rel = idx - 505712;
            wct[(OUTC + rel % OUTC) * (long)HID + rel / OUTC] = f2bu(v);
        }
    } else if (idx < CVT_TOT + PACK_THREADS) {
        int j = idx - CVT_TOT;   // 4 edges per thread
        int r0, r1, r2, r3, c0, c1, c2, c3;
        if (iw) {
            const int4* pr = (const int4*)ei;
            const int4* pc = (const int4*)(ei + 2L * NED);
            int4 ra = pr[2 * j], rb = pr[2 * j + 1];
            int4 ca = pc[2 * j], cb = pc[2 * j + 1];
            r0 = ra.x; r1 = ra.z; r2 = rb.x; r3 = rb.z;
            c0 = ca.x; c1 = ca.z; c2 = cb.x; c3 = cb.z;
        } else {
            int4 ra = ((const int4*)ei)[j];
            int4 ca = ((const int4*)(ei + NED))[j];
            r0 = ra.x; r1 = ra.y; r2 = ra.z; r3 = ra.w;
            c0 = ca.x; c1 = ca.y; c2 = ca.z; c3 = ca.w;
        }
        uint4 out;
        out.x = (unsigned)r0 | ((unsigned)c0 << 16);
        out.y = (unsigned)r1 | ((unsigned)c1 << 16);
        out.z = (unsigned)r2 | ((unsigned)c2 << 16);
        out.w = (unsigned)r3 | ((unsigned)c3 << 16);
        ((uint4*)pk)[j] = out;
    }
}

// K2: window-sweep degree count. Block b owns dest window [b*512, +512).
// LDS histogram (LDS atomics only), LDS pair+Hillis-Steele scan, then PLAIN
// coalesced stores of cnt/start/dis. Region base = b*CAPB (fixed capacity,
// Poisson(8192)+8.5sigma — overflow-guarded in k_place).
__global__ __launch_bounds__(256) void k_count(const unsigned int* pk,
                                               int* cnt, int* start, float* F) {
    __shared__ int hist[SPAN];
    __shared__ int lds[256];
    int tid = threadIdx.x;
    hist[tid] = 0; hist[tid + 256] = 0;
    __syncthreads();
    unsigned int lo = (unsigned int)blockIdx.x * SPAN;
    const uint4* pk4 = (const uint4*)pk;
    for (int g = tid; g < NED / 4; g += 256) {
        uint4 e = pk4[g];
        unsigned int c;
        c = (e.x >> 16) - lo; if (c < SPAN) atomicAdd(&hist[c], 1);
        c = (e.y >> 16) - lo; if (c < SPAN) atomicAdd(&hist[c], 1);
        c = (e.z >> 16) - lo; if (c < SPAN) atomicAdd(&hist[c], 1);
        c = (e.w >> 16) - lo; if (c < SPAN) atomicAdd(&hist[c], 1);
    }
    __syncthreads();
    int h0 = hist[2 * tid], h1 = hist[2 * tid + 1];
    int pair = h0 + h1;
    lds[tid] = pair;
    __syncthreads();
    int incl = pair;
    for (int off = 1; off < 256; off <<= 1) {
        int t = (tid >= off) ? lds[tid - off] : 0;
        __syncthreads();
        incl += t; lds[tid] = incl;
        __syncthreads();
    }
    int base = blockIdx.x * CAPB + (incl - pair);
    int g0 = blockIdx.x * SPAN + 2 * tid;
    if (g0 < NND) {
        cnt[g0] = h0; start[g0] = base;
        F[DIS_O + g0] = rsqrtf((float)h0 + 1.0f);
    }
    if (g0 + 1 < NND) {
        cnt[g0 + 1] = h1; start[g0 + 1] = base + h0;
        F[DIS_O + g0 + 1] = rsqrtf((float)h1 + 1.0f);
    }
}

// K3: window-sweep placement. LDS cursors (from start[]), records {src, fp32
// norm} written into the block's PRIVATE contiguous region -> lines fill in
// one XCD's L2 before eviction (kills the 32B-sector write amplification).
__global__ __launch_bounds__(256) void k_place(const unsigned int* pk, const int* start,
                                               const float* F, int2* edges) {
    __shared__ int cur[SPAN];
    __shared__ float dloc[SPAN];
    int tid = threadIdx.x;
    unsigned int lo = (unsigned int)blockIdx.x * SPAN;
    {
        int g0 = lo + tid, g1 = lo + 256 + tid;
        cur[tid]        = (g0 < NND) ? start[g0] : 0;
        cur[tid + 256]  = (g1 < NND) ? start[g1] : 0;
        dloc[tid]       = (g0 < NND) ? F[DIS_O + g0] : 0.0f;
        dloc[tid + 256] = (g1 < NND) ? F[DIS_O + g1] : 0.0f;
    }
    __syncthreads();
    int lim = (blockIdx.x + 1) * CAPB;
    const uint4* pk4 = (const uint4*)pk;
    for (int g = tid; g < NED / 4; g += 256) {
        uint4 e = pk4[g];
#pragma unroll
        for (int q = 0; q < 4; ++q) {
            unsigned int w = (q == 0) ? e.x : (q == 1) ? e.y : (q == 2) ? e.z : e.w;
            unsigned int c = (w >> 16) - lo;
            if (c < SPAN) {
                int r = (int)(w & 0xffffu);
                int pos = atomicAdd(&cur[c], 1);
                float nrm = F[DIS_O + r] * dloc[c];
                if (pos < lim) edges[pos] = make_int2(r, __float_as_int(nrm));
            }
        }
    }
}

// K4: fused layer1 — FOUR threads per node (quad in-wave): each takes every
// 4th edge, butterfly-combines the 10 partials, then emits 24 of 96 h feats.
__global__ __launch_bounds__(256) void k_layer1(const int* cnt, const int* start,
                                                const int2* edges, const float* F,
                                                unsigned short* h) {
    __shared__ float w1s[1056];   // W1 (960) then b1 (96), contiguous in F
    for (int i = threadIdx.x; i < 1056; i += 256) w1s[i] = F[W1F_O + i];
    __syncthreads();
    int idx = blockIdx.x * 256 + threadIdx.x;
    if (idx >= NND * 4) return;
    int node = idx >> 2, sub = idx & 3;
    int s = start[node], t = s + cnt[node];
    float ax[INC];
#pragma unroll
    for (int j = 0; j < INC; ++j) ax[j] = 0.0f;
    for (int k = s + sub; k < t; k += 4) {
        int2 rec = edges[k];
        float n = __int_as_float(rec.y);
        const float2* xr = (const float2*)(F + XF_O + (long)rec.x * INC);
#pragma unroll
        for (int j = 0; j < 5; ++j) {
            float2 v = xr[j];
            ax[2 * j]     = fmaf(n, v.x, ax[2 * j]);
            ax[2 * j + 1] = fmaf(n, v.y, ax[2 * j + 1]);
        }
    }
    if (sub == 0) {   // self-loop: weight dis^2 = 1/(deg+1)
        float d = F[DIS_O + node]; float dd = d * d;
        const float2* xr = (const float2*)(F + XF_O + (long)node * INC);
#pragma unroll
        for (int j = 0; j < 5; ++j) {
            float2 v = xr[j];
            ax[2 * j]     = fmaf(dd, v.x, ax[2 * j]);
            ax[2 * j + 1] = fmaf(dd, v.y, ax[2 * j + 1]);
        }
    }
    // quad butterfly (quads are wave-aligned: masks 1,2 stay inside the quad)
#pragma unroll
    for (int j = 0; j < INC; ++j) {
        ax[j] += __shfl_xor(ax[j], 1, 64);
        ax[j] += __shfl_xor(ax[j], 2, 64);
    }
    int f0 = sub * 24;
    unsigned int* hrow = (unsigned int*)(h + (size_t)node * HID);
#pragma unroll
    for (int f = f0; f < f0 + 24; f += 2) {
        float a0 = w1s[960 + f], a1 = w1s[960 + f + 1];
#pragma unroll
        for (int kk = 0; kk < INC; ++kk) {
            a0 = fmaf(ax[kk], w1s[kk * HID + f], a0);
            a1 = fmaf(ax[kk], w1s[kk * HID + f + 1], a1);
        }
        a0 = fmaxf(a0, 0.0f); a1 = fmaxf(a1, 0.0f);
        unsigned int u0 = f2bu(a0), u1 = f2bu(a1);
        hrow[f >> 1] = u0 | (u1 << 16);
    }
}

// K5: pure gather-aggregate — one wave per node, lanes 0..47 hold feature
// pairs (2L,2L+1), 8-edge unroll, self-loop, write v as packed bf16.
__global__ __launch_bounds__(256) void k_gaggh(const int* cnt, const int* start,
                                               const int2* edges, const float* F,
                                               const unsigned short* h, unsigned int* v) {
    int wid = threadIdx.x >> 6;
    int lane = threadIdx.x & 63;
    int node = blockIdx.x * 4 + wid;
    if (lane >= 48) return;
    const unsigned int* hb = (const unsigned int*)h;

    int s = start[node], t = s + cnt[node];
    float a0 = 0.0f, a1 = 0.0f;
    int k = s;
    for (; k + 7 < t; k += 8) {
        int2 e0 = edges[k],     e1 = edges[k + 1], e2 = edges[k + 2], e3 = edges[k + 3];
        int2 e4 = edges[k + 4], e5 = edges[k + 5], e6 = edges[k + 6], e7 = edges[k + 7];
        unsigned int p0 = hb[(size_t)e0.x * 48 + lane];
        unsigned int p1 = hb[(size_t)e1.x * 48 + lane];
        unsigned int p2 = hb[(size_t)e2.x * 48 + lane];
        unsigned int p3 = hb[(size_t)e3.x * 48 + lane];
        unsigned int p4 = hb[(size_t)e4.x * 48 + lane];
        unsigned int p5 = hb[(size_t)e5.x * 48 + lane];
        unsigned int p6 = hb[(size_t)e6.x * 48 + lane];
        unsigned int p7 = hb[(size_t)e7.x * 48 + lane];
        a0 = fmaf(__int_as_float(e0.y), bfLo(p0), a0); a1 = fmaf(__int_as_float(e0.y), bfHi(p0), a1);
        a0 = fmaf(__int_as_float(e1.y), bfLo(p1), a0); a1 = fmaf(__int_as_float(e1.y), bfHi(p1), a1);
        a0 = fmaf(__int_as_float(e2.y), bfLo(p2), a0); a1 = fmaf(__int_as_float(e2.y), bfHi(p2), a1);
        a0 = fmaf(__int_as_float(e3.y), bfLo(p3), a0); a1 = fmaf(__int_as_float(e3.y), bfHi(p3), a1);
        a0 = fmaf(__int_as_float(e4.y), bfLo(p4), a0); a1 = fmaf(__int_as_float(e4.y), bfHi(p4), a1);
        a0 = fmaf(__int_as_float(e5.y), bfLo(p5), a0); a1 = fmaf(__int_as_float(e5.y), bfHi(p5), a1);
        a0 = fmaf(__int_as_float(e6.y), bfLo(p6), a0); a1 = fmaf(__int_as_float(e6.y), bfHi(p6), a1);
        a0 = fmaf(__int_as_float(e7.y), bfLo(p7), a0); a1 = fmaf(__int_as_float(e7.y), bfHi(p7), a1);
    }
    for (; k < t; ++k) {
        int2 e0 = edges[k];
        unsigned int p0 = hb[(size_t)e0.x * 48 + lane];
        a0 = fmaf(__int_as_float(e0.y), bfLo(p0), a0); a1 = fmaf(__int_as_float(e0.y), bfHi(p0), a1);
    }
    float d = F[DIS_O + node]; float dd = d * d;
    unsigned int ps = hb[(size_t)node * 48 + lane];
    a0 = fmaf(dd, bfLo(ps), a0); a1 = fmaf(dd, bfHi(ps), a1);
    v[(size_t)node * 48 + lane] = (unsigned int)f2bu(a0) | ((unsigned int)f2bu(a1) << 16);
}

// K6: MFMA head GEMM — v[50000,96]bf16 @ WcatT^T + bias -> d_out.
__global__ __launch_bounds__(256) void k_heads(const unsigned short* v, const unsigned short* wct,
                                               const float* F, const int* flags, void* dout) {
    int wid = threadIdx.x >> 6;
    int lane = threadIdx.x & 63;
    int mtile = blockIdx.x * 4 + wid;
    if (mtile >= MTILES) return;
    int l16 = lane & 15, quad = lane >> 4;

    const unsigned short* vb = v + ((size_t)mtile * 16 + l16) * HID + quad * 8;
    short8 afr0 = *(const short8*)(vb);
    short8 afr1 = *(const short8*)(vb + 32);
    short8 afr2 = *(const short8*)(vb + 64);

    int ff = flags[1];
#pragma unroll
    for (int nt = 0; nt < 6; ++nt) {
        const unsigned short* wb = wct + ((size_t)nt * 16 + l16) * HID + quad * 8;
        short8 b0 = *(const short8*)(wb);
        short8 b1 = *(const short8*)(wb + 32);
        short8 b2 = *(const short8*)(wb + 64);
        f32x4 acc = {0.0f, 0.0f, 0.0f, 0.0f};
        acc = __builtin_amdgcn_mfma_f32_16x16x32_bf16(afr0, b0, acc, 0, 0, 0);
        acc = __builtin_amdgcn_mfma_f32_16x16x32_bf16(afr1, b1, acc, 0, 0, 0);
        acc = __builtin_amdgcn_mfma_f32_16x16x32_bf16(afr2, b2, acc, 0, 0, 0);
        int n = nt * 16 + l16;                 // 0..95: <48 mu, >=48 logstd
        float bias = (n < OUTC) ? F[BMF_O + n] : F[BLF_O + n - OUTC];
        long obase = (n < OUTC) ? ((long)n) : (NOUT + (long)(n - OUTC));
#pragma unroll
        for (int r = 0; r < 4; ++r) {
            int m = mtile * 16 + quad * 4 + r;
            float val = acc[r] + bias;
            long oi = (long)m * OUTC + obase;
            if (ff) ((float*)dout)[oi] = val;
            else    ((bf16*)dout)[oi] = __float2bfloat16(val);
        }
    }
}

extern "C" void kernel_launch(void* const* d_in, const int* in_sizes, int n_in,
                              void* d_out, int out_size, void* d_ws, size_t ws_size,
                              hipStream_t stream) {
    const int* ei = (const int*)d_in[1];
    int* flags = (int*)d_ws;
    float* F = (float*)((char*)d_ws + 256);
    unsigned short* h   = (unsigned short*)(F + FLOATS_TOT);
    unsigned short* wct = h + (size_t)NND * HID;
    unsigned short* vv  = wct + (size_t)HID * HID;
    int* cnt   = (int*)(vv + (size_t)NND * HID);
    int* start = cnt + NND;
    unsigned int* pk = (unsigned int*)(start + NND);
    int2* edges = (int2*)(pk + NED);

    k_prep<<<(CVT_TOT + PACK_THREADS + 255) / 256, 256, 0, stream>>>(
        d_in[0], d_in[2], d_in[3], d_in[4], d_in[5], d_in[6], d_in[7], ei, flags, F, wct, pk);
    k_count<<<CBLK, 256, 0, stream>>>(pk, cnt, start, F);
    k_place<<<CBLK, 256, 0, stream>>>(pk, start, F, edges);
    k_layer1<<<(NND * 4 + 255) / 256, 256, 0, stream>>>(cnt, start, edges, F, h);
    k_gaggh<<<NND / 4, 256, 0, stream>>>(cnt, start, edges, F, h, (unsigned int*)vv);
    k_heads<<<(MTILES + 3) / 4, 256, 0, stream>>>(vv, wct, F, flags, d_out);
}

// Round 11
// 171.083 us; speedup vs baseline: 5.0305x; 5.0305x over previous
//
#include <hip/hip_runtime.h>
#include <hip/hip_bf16.h>

// Problem constants
#define NND 50000      // nodes
#define NED 800000     // edges (without self-loops)
#define INC 10
#define HID 96
#define OUTC 48
#define NOUT (NND*OUTC)
#define MTILES 3125    // 50000 / 16
#define NW 98          // dest windows of SPAN nodes
#define SPAN 512
#define EW_CAP 9216    // CSR capacity per window (Poisson 8163 + 11 sigma)
#define PB 200         // phase-1 blocks
#define PBE 4000       // edges per phase-1 block (exact: 200*4000 = 800000)

typedef __hip_bfloat16 bf16;
typedef __attribute__((ext_vector_type(8))) short short8;
typedef __attribute__((ext_vector_type(4))) float f32x4;

// ---- workspace layout ----
// header ints: [0..1] flags (k_prep block 0). 256B reserved.
// F floats (from d_ws+256):
#define XF_O   0L                 // 500000  x fp32
#define W1F_O  500000L            // 960 (W1 then b1: 1056 contiguous)
#define B1F_O  500960L            // 96
#define WMF_O  501056L            // 4608 (fp32 copy; heads use bf16 wct)
#define BMF_O  505664L            // 48
#define WLF_O  505712L            // 4608
#define BLF_O  510320L            // 48
#define DIS_O  510368L            // 50000 rsqrt(deg+1)   (k_win)
#define XS_O   560368L            // 500000 x' = dis*x    (k_win)
#define FLOATS_TOT 1060368L
// then: h' [NND*96] bf16 (dis-prescaled hidden), wct [96*96] bf16, v [NND*96] bf16
// then ints: cnt[50000], start[50000], pk[800000], part[800000],
//            smat[NW*PB], cmat[NW*PB]; then csr u16 [NW*EW_CAP]

__device__ __forceinline__ float b2f(bf16 v) { return __bfloat162float(v); }
__device__ __forceinline__ float bfLo(unsigned int p) { return __uint_as_float(p << 16); }
__device__ __forceinline__ float bfHi(unsigned int p) { return __uint_as_float(p & 0xffff0000u); }
__device__ __forceinline__ unsigned short f2bu(float v) {
    return __bfloat16_as_ushort(__float2bfloat16(v));
}

// K1: block-local dtype sniff + convert-to-fp32 + bf16 transposed head-weight
//     build + edge pack (row | col<<16). No global atomics.
#define CVT_TOT 510368
#define PACK_THREADS 200000
__global__ __launch_bounds__(256) void k_prep(const void* x, const void* w1, const void* b1,
                                              const void* wm, const void* bm,
                                              const void* wl, const void* bl,
                                              const int* ei, int* flags,
                                              float* F, unsigned short* wct,
                                              unsigned int* pk) {
    __shared__ int s_oddnz, s_big;
    if (threadIdx.x == 0) { s_oddnz = 0; s_big = 0; }
    __syncthreads();
    {
        int t = threadIdx.x;
        if (t < 128) {
            if (ei[2 * t + 1] != 0) atomicOr(&s_oddnz, 1);
        }
        const unsigned short* xs = (const unsigned short*)x;
        unsigned short u = xs[t * 8];
        float f = __uint_as_float(((unsigned int)u) << 16);
        int big = !(fabsf(f) < 64.0f);
        unsigned short u2 = xs[t * 8 + 5];
        float f2 = __uint_as_float(((unsigned int)u2) << 16);
        big |= !(fabsf(f2) < 64.0f);
        if (big) atomicOr(&s_big, 1);
    }
    __syncthreads();
    int iw = (s_oddnz == 0) ? 1 : 0;   // 1 = int64 edge_index
    int ff = s_big ? 1 : 0;            // 1 = fp32 floats
    if (blockIdx.x == 0 && threadIdx.x == 0) { flags[0] = iw; flags[1] = ff; }

    int idx = blockIdx.x * 256 + threadIdx.x;
    if (idx < CVT_TOT) {
        const void* src; long off;
        if      (idx < 500000) { src = x;  off = idx; }
        else if (idx < 500960) { src = w1; off = idx - 500000; }
        else if (idx < 501056) { src = b1; off = idx - 500960; }
        else if (idx < 505664) { src = wm; off = idx - 501056; }
        else if (idx < 505712) { src = bm; off = idx - 505664; }
        else if (idx < 510320) { src = wl; off = idx - 505712; }
        else                   { src = bl; off = idx - 510320; }
        float v = ff ? ((const float*)src)[off] : b2f(((const bf16*)src)[off]);
        F[idx] = v;
        if (idx >= 501056 && idx < 505664) {          // W_mu[k][j] -> wct[j][k]
            long rel = idx - 501056;
            wct[(rel % OUTC) * (long)HID + rel / OUTC] = f2bu(v);
        } else if (idx >= 505712 && idx < 510320) {   // W_ls[k][j] -> wct[48+j][k]
            long rel = idx - 505712;
            wct[(OUTC + rel % OUTC) * (long)HID + rel / OUTC] = f2bu(v);
        }
    } else if (idx < CVT_TOT + PACK_THREADS) {
        int j = idx - CVT_TOT;   // 4 edges per thread
        int r0, r1, r2, r3, c0, c1, c2, c3;
        if (iw) {
            const int4* pr = (const int4*)ei;
            const int4* pc = (const int4*)(ei + 2L * NED);
            int4 ra = pr[2 * j], rb = pr[2 * j + 1];
            int4 ca = pc[2 * j], cb = pc[2 * j + 1];
            r0 = ra.x; r1 = ra.z; r2 = rb.x; r3 = rb.z;
            c0 = ca.x; c1 = ca.z; c2 = cb.x; c3 = cb.z;
        } else {
            int4 ra = ((const int4*)ei)[j];
            int4 ca = ((const int4*)(ei + NED))[j];
            r0 = ra.x; r1 = ra.y; r2 = ra.z; r3 = ra.w;
            c0 = ca.x; c1 = ca.y; c2 = ca.z; c3 = ca.w;
        }
        uint4 out;
        out.x = (unsigned)r0 | ((unsigned)c0 << 16);
        out.y = (unsigned)r1 | ((unsigned)c1 << 16);
        out.z = (unsigned)r2 | ((unsigned)c2 << 16);
        out.w = (unsigned)r3 | ((unsigned)c3 << 16);
        ((uint4*)pk)[j] = out;
    }
}

// K2: phase-1 partition. Block b owns edges [b*4000, +4000): LDS-bucket them
// by dest window (c>>9), write back as one coalesced 16 KB run + run matrix
// smat/cmat[w][b]. All atomics in LDS; global writes sequential.
__global__ __launch_bounds__(256) void k_part(const unsigned int* pk, unsigned int* part,
                                              int* smat, int* cmat) {
    __shared__ int counts[NW];
    __shared__ int offs[NW];
    __shared__ int cur[NW];
    __shared__ unsigned int buf[PBE];
    int tid = threadIdx.x;
    for (int i = tid; i < NW; i += 256) counts[i] = 0;
    __syncthreads();
    int base4 = blockIdx.x * (PBE / 4);
    const uint4* pk4 = (const uint4*)pk;
    for (int g = tid; g < PBE / 4; g += 256) {
        uint4 e = pk4[base4 + g];
        atomicAdd(&counts[(e.x >> 16) >> 9], 1);
        atomicAdd(&counts[(e.y >> 16) >> 9], 1);
        atomicAdd(&counts[(e.z >> 16) >> 9], 1);
        atomicAdd(&counts[(e.w >> 16) >> 9], 1);
    }
    __syncthreads();
    if (tid < NW) {   // parallel O(NW^2) exclusive scan (tiny)
        int run = 0;
        for (int j = 0; j < tid; ++j) run += counts[j];
        offs[tid] = run; cur[tid] = run;
        cmat[tid * PB + blockIdx.x] = counts[tid];
        smat[tid * PB + blockIdx.x] = blockIdx.x * PBE + run;
    }
    __syncthreads();
    for (int g = tid; g < PBE / 4; g += 256) {
        uint4 e = pk4[base4 + g];
#pragma unroll
        for (int q = 0; q < 4; ++q) {
            unsigned int w = (q == 0) ? e.x : (q == 1) ? e.y : (q == 2) ? e.z : e.w;
            int pos = atomicAdd(&cur[(w >> 16) >> 9], 1);
            buf[pos] = w;
        }
    }
    __syncthreads();
    for (int i = tid; i < PBE; i += 256) part[blockIdx.x * PBE + i] = buf[i];
}

// K3: phase-2 window build. Block w reads only its ~200 runs (~33 KB, L2-hot):
// LDS histogram (512 nodes) -> scan -> cnt/start/dis/x' writes (coalesced) ->
// LDS-cursor place of u16 src records into the window's PRIVATE 18 KB CSR
// segment (lines fill before eviction). Wave-per-run processing, 16 waves.
__global__ __launch_bounds__(1024) void k_win(const unsigned int* part, const int* smat,
                                              const int* cmat, float* F,
                                              int* cnt, int* start, unsigned short* csr) {
    __shared__ int Lrun[PB], Srun[PB];
    __shared__ int hist[SPAN], st[SPAN], cur[SPAN];
    __shared__ float dl[SPAN];
    int tid = threadIdx.x;
    int w = blockIdx.x;
    if (tid < PB) { Lrun[tid] = cmat[w * PB + tid]; Srun[tid] = smat[w * PB + tid]; }
    if (tid < SPAN) hist[tid] = 0;
    __syncthreads();
    unsigned int lo = (unsigned)w * SPAN;
    int wave = tid >> 6, lane = tid & 63;
    for (int rb = wave; rb < PB; rb += 16) {
        int L = Lrun[rb], S = Srun[rb];
        for (int i = lane; i < L; i += 64)
            atomicAdd(&hist[(part[S + i] >> 16) - lo], 1);
    }
    __syncthreads();
    if (tid < SPAN) st[tid] = hist[tid];
    __syncthreads();
    for (int off = 1; off < SPAN; off <<= 1) {
        int t = (tid < SPAN && tid >= off) ? st[tid - off] : 0;
        __syncthreads();
        if (tid < SPAN) st[tid] += t;
        __syncthreads();
    }
    if (tid < SPAN) {
        int h0 = hist[tid];
        int abs0 = w * EW_CAP + (st[tid] - h0);
        cur[tid] = abs0;
        float dis = rsqrtf((float)h0 + 1.0f);
        dl[tid] = dis;
        int g = (int)lo + tid;
        if (g < NND) {
            cnt[g] = h0; start[g] = abs0;
            F[DIS_O + g] = dis;
        }
    }
    __syncthreads();
    // x' = dis * x for this window's nodes (coalesced read+write)
    for (int i = tid; i < SPAN * INC; i += 1024) {
        int node = (int)lo + i / INC;
        if (node < NND)
            F[XS_O + (long)node * INC + (i % INC)] =
                dl[i / INC] * F[XF_O + (long)node * INC + (i % INC)];
    }
    int lim = (w + 1) * EW_CAP;
    for (int rb = wave; rb < PB; rb += 16) {
        int L = Lrun[rb], S = Srun[rb];
        for (int i = lane; i < L; i += 64) {
            unsigned int e = part[S + i];
            int pos = atomicAdd(&cur[(e >> 16) - lo], 1);
            if (pos < lim) csr[pos] = (unsigned short)(e & 0xffffu);
        }
    }
}

// K4: fused layer1 — FOUR threads per node (quad in-wave), u16 records,
// x' gather (no per-edge norm), butterfly, scale by dis_c, GEMV via LDS W1,
// write h' = dis_c * relu(...) as packed bf16.
__global__ __launch_bounds__(256) void k_layer1(const int* cnt, const int* start,
                                                const unsigned short* csr, const float* F,
                                                unsigned short* h) {
    __shared__ float w1s[1056];   // W1 (960) then b1 (96), contiguous in F
    for (int i = threadIdx.x; i < 1056; i += 256) w1s[i] = F[W1F_O + i];
    __syncthreads();
    int idx = blockIdx.x * 256 + threadIdx.x;
    if (idx >= NND * 4) return;
    int node = idx >> 2, sub = idx & 3;
    int s = start[node], t = s + cnt[node];
    int lim = ((node >> 9) + 1) * EW_CAP;
    if (t > lim) t = lim;                 // capacity guard (P ~ 1e-27)
    float ax[INC];
#pragma unroll
    for (int j = 0; j < INC; ++j) ax[j] = 0.0f;
    for (int k = s + sub; k < t; k += 4) {
        int src = csr[k];
        const float2* xr = (const float2*)(F + XS_O + (long)src * INC);
#pragma unroll
        for (int j = 0; j < 5; ++j) {
            float2 v = xr[j];
            ax[2 * j]     += v.x;
            ax[2 * j + 1] += v.y;
        }
    }
    if (sub == 0) {   // self term: + x'_c
        const float2* xr = (const float2*)(F + XS_O + (long)node * INC);
#pragma unroll
        for (int j = 0; j < 5; ++j) {
            float2 v = xr[j];
            ax[2 * j]     += v.x;
            ax[2 * j + 1] += v.y;
        }
    }
    // quad butterfly (quads are wave-aligned: masks 1,2 stay inside the quad)
#pragma unroll
    for (int j = 0; j < INC; ++j) {
        ax[j] += __shfl_xor(ax[j], 1, 64);
        ax[j] += __shfl_xor(ax[j], 2, 64);
    }
    float dn = F[DIS_O + node];
#pragma unroll
    for (int j = 0; j < INC; ++j) ax[j] *= dn;   // agg = dis_c * (sum + self)
    int f0 = sub * 24;
    unsigned int* hrow = (unsigned int*)(h + (size_t)node * HID);
#pragma unroll
    for (int f = f0; f < f0 + 24; f += 2) {
        float a0 = w1s[960 + f], a1 = w1s[960 + f + 1];
#pragma unroll
        for (int kk = 0; kk < INC; ++kk) {
            a0 = fmaf(ax[kk], w1s[kk * HID + f], a0);
            a1 = fmaf(ax[kk], w1s[kk * HID + f + 1], a1);
        }
        a0 = fmaxf(a0, 0.0f) * dn;     // h' = dis_c * relu(...)
        a1 = fmaxf(a1, 0.0f) * dn;
        unsigned int u0 = f2bu(a0), u1 = f2bu(a1);
        hrow[f >> 1] = u0 | (u1 << 16);
    }
}

// K5: gather-aggregate — one wave per node, lanes 0..47 = feature pairs,
// pure-add inner loop over h' (prescaled), final scale by dis_c, v bf16.
__global__ __launch_bounds__(256) void k_gaggh(const int* cnt, const int* start,
                                               const unsigned short* csr, const float* F,
                                               const unsigned short* h, unsigned int* v) {
    int wid = threadIdx.x >> 6;
    int lane = threadIdx.x & 63;
    int node = blockIdx.x * 4 + wid;
    if (lane >= 48) return;
    const unsigned int* hb = (const unsigned int*)h;

    int s = start[node], t = s + cnt[node];
    int lim = ((node >> 9) + 1) * EW_CAP;
    if (t > lim) t = lim;
    float a0 = 0.0f, a1 = 0.0f;
    int k = s;
    for (; k + 7 < t; k += 8) {
        int s0 = csr[k],     s1 = csr[k + 1], s2 = csr[k + 2], s3 = csr[k + 3];
        int s4 = csr[k + 4], s5 = csr[k + 5], s6 = csr[k + 6], s7 = csr[k + 7];
        unsigned int p0 = hb[(size_t)s0 * 48 + lane];
        unsigned int p1 = hb[(size_t)s1 * 48 + lane];
        unsigned int p2 = hb[(size_t)s2 * 48 + lane];
        unsigned int p3 = hb[(size_t)s3 * 48 + lane];
        unsigned int p4 = hb[(size_t)s4 * 48 + lane];
        unsigned int p5 = hb[(size_t)s5 * 48 + lane];
        unsigned int p6 = hb[(size_t)s6 * 48 + lane];
        unsigned int p7 = hb[(size_t)s7 * 48 + lane];
        a0 += bfLo(p0); a1 += bfHi(p0);
        a0 += bfLo(p1); a1 += bfHi(p1);
        a0 += bfLo(p2); a1 += bfHi(p2);
        a0 += bfLo(p3); a1 += bfHi(p3);
        a0 += bfLo(p4); a1 += bfHi(p4);
        a0 += bfLo(p5); a1 += bfHi(p5);
        a0 += bfLo(p6); a1 += bfHi(p6);
        a0 += bfLo(p7); a1 += bfHi(p7);
    }
    for (; k < t; ++k) {
        unsigned int p0 = hb[(size_t)csr[k] * 48 + lane];
        a0 += bfLo(p0); a1 += bfHi(p0);
    }
    unsigned int ps = hb[(size_t)node * 48 + lane];   // + h'_c (self)
    a0 += bfLo(ps); a1 += bfHi(ps);
    float dn = F[DIS_O + node];
    a0 *= dn; a1 *= dn;                                // v = dis_c * (...)
    v[(size_t)node * 48 + lane] = (unsigned int)f2bu(a0) | ((unsigned int)f2bu(a1) << 16);
}

// K6: MFMA head GEMM — v[50000,96]bf16 @ WcatT^T + bias -> d_out.
__global__ __launch_bounds__(256) void k_heads(const unsigned short* v, const unsigned short* wct,
                                               const float* F, const int* flags, void* dout) {
    int wid = threadIdx.x >> 6;
    int lane = threadIdx.x & 63;
    int mtile = blockIdx.x * 4 + wid;
    if (mtile >= MTILES) return;
    int l16 = lane & 15, quad = lane >> 4;

    const unsigned short* vb = v + ((size_t)mtile * 16 + l16) * HID + quad * 8;
    short8 afr0 = *(const short8*)(vb);
    short8 afr1 = *(const short8*)(vb + 32);
    short8 afr2 = *(const short8*)(vb + 64);

    int ff = flags[1];
#pragma unroll
    for (int nt = 0; nt < 6; ++nt) {
        const unsigned short* wb = wct + ((size_t)nt * 16 + l16) * HID + quad * 8;
        short8 b0 = *(const short8*)(wb);
        short8 b1 = *(const short8*)(wb + 32);
        short8 b2 = *(const short8*)(wb + 64);
        f32x4 acc = {0.0f, 0.0f, 0.0f, 0.0f};
        acc = __builtin_amdgcn_mfma_f32_16x16x32_bf16(afr0, b0, acc, 0, 0, 0);
        acc = __builtin_amdgcn_mfma_f32_16x16x32_bf16(afr1, b1, acc, 0, 0, 0);
        acc = __builtin_amdgcn_mfma_f32_16x16x32_bf16(afr2, b2, acc, 0, 0, 0);
        int n = nt * 16 + l16;                 // 0..95: <48 mu, >=48 logstd
        float bias = (n < OUTC) ? F[BMF_O + n] : F[BLF_O + n - OUTC];
        long obase = (n < OUTC) ? ((long)n) : (NOUT + (long)(n - OUTC));
#pragma unroll
        for (int r = 0; r < 4; ++r) {
            int m = mtile * 16 + quad * 4 + r;
            float val = acc[r] + bias;
            long oi = (long)m * OUTC + obase;
            if (ff) ((float*)dout)[oi] = val;
            else    ((bf16*)dout)[oi] = __float2bfloat16(val);
        }
    }
}

extern "C" void kernel_launch(void* const* d_in, const int* in_sizes, int n_in,
                              void* d_out, int out_size, void* d_ws, size_t ws_size,
                              hipStream_t stream) {
    const int* ei = (const int*)d_in[1];
    int* flags = (int*)d_ws;
    float* F = (float*)((char*)d_ws + 256);
    unsigned short* h   = (unsigned short*)(F + FLOATS_TOT);
    unsigned short* wct = h + (size_t)NND * HID;
    unsigned short* vv  = wct + (size_t)HID * HID;
    int* cnt   = (int*)(vv + (size_t)NND * HID);
    int* start = cnt + NND;
    unsigned int* pk   = (unsigned int*)(start + NND);
    unsigned int* part = pk + NED;
    int* smat = (int*)(part + NED);
    int* cmat = smat + NW * PB;
    unsigned short* csr = (unsigned short*)(cmat + NW * PB);

    k_prep<<<(CVT_TOT + PACK_THREADS + 255) / 256, 256, 0, stream>>>(
        d_in[0], d_in[2], d_in[3], d_in[4], d_in[5], d_in[6], d_in[7], ei, flags, F, wct, pk);
    k_part<<<PB, 256, 0, stream>>>(pk, part, smat, cmat);
    k_win<<<NW, 1024, 0, stream>>>(part, smat, cmat, F, cnt, start, csr);
    k_layer1<<<(NND * 4 + 255) / 256, 256, 0, stream>>>(cnt, start, csr, F, h);
    k_gaggh<<<NND / 4, 256, 0, stream>>>(cnt, start, csr, F, h, (unsigned int*)vv);
    k_heads<<<(MTILES + 3) / 4, 256, 0, stream>>>(vv, wct, F, flags, d_out);
}

// Round 12
// 166.773 us; speedup vs baseline: 5.1605x; 1.0258x over previous
//
#include <hip/hip_runtime.h>
#include <hip/hip_bf16.h>

// Problem constants
#define NND 50000      // nodes
#define NED 800000     // edges (without self-loops)
#define INC 10
#define HID 96
#define OUTC 48
#define NOUT (NND*OUTC)
#define MTILES 3125    // 50000 / 16
#define NW 98          // dest windows of SPAN nodes
#define SPAN 512
#define EW_CAP 9216    // CSR capacity per window (Poisson 8163 + 11 sigma)
#define PB 200         // partition blocks
#define PBE 4000       // edges per partition block (200*4000 = 800000 exact)

typedef __hip_bfloat16 bf16;
typedef __attribute__((ext_vector_type(8))) short short8;
typedef __attribute__((ext_vector_type(4))) float f32x4;

// ---- workspace layout ----
// header ints: [0..1] flags (k_part block 0). 256B reserved.
// F floats (from d_ws+256):
#define W1F_O  0L                 // 960 (W1 then b1: 1056 contiguous)
#define B1F_O  960L               // 96
#define BMF_O  1056L              // 48
#define BLF_O  1104L              // 48
#define DIS_O  1152L              // 50000 rsqrt(deg+1)   (k_win)
#define XS_O   51152L             // 500000 x' = dis*x    (k_win, fp32)
#define FLOATS_TOT 551152L
// then: h' [NND*96] bf16 (dis-prescaled hidden), wct [96*96] bf16, v [NND*96] bf16
// then ints: cnt[50000], start[50000], part[800000], smat[NW*PB], cmat[NW*PB];
// then csr u16 [NW*EW_CAP]

__device__ __forceinline__ float b2f(bf16 v) { return __bfloat162float(v); }
__device__ __forceinline__ float bfLo(unsigned int p) { return __uint_as_float(p << 16); }
__device__ __forceinline__ float bfHi(unsigned int p) { return __uint_as_float(p & 0xffff0000u); }
__device__ __forceinline__ unsigned short f2bu(float v) {
    return __bfloat16_as_ushort(__float2bfloat16(v));
}

// K1: partition + weights. Block b owns edges [b*4000,+4000): block-local sniff,
// read edge slice ONCE into registers (16 packed words/thread), LDS histogram by
// dest window (c>>9), LDS scan, LDS place, coalesced 16 KB run write + run
// matrix. Blocks 0..40 additionally convert the 10368 weight/bias elements
// (W1+b1+biases -> fp32 F; W_mu/W_ls -> transposed bf16 wct). No global atomics.
__global__ __launch_bounds__(256) void k_part(const int* ei, const void* x,
                                              const void* w1, const void* b1,
                                              const void* wm, const void* bm,
                                              const void* wl, const void* bl,
                                              int* flags, float* F, unsigned short* wct,
                                              unsigned int* part, int* smat, int* cmat) {
    __shared__ int s_oddnz, s_big;
    __shared__ int counts[NW], cur[NW];
    __shared__ unsigned int buf[PBE];
    int tid = threadIdx.x;
    if (tid == 0) { s_oddnz = 0; s_big = 0; }
    for (int i = tid; i < NW; i += 256) counts[i] = 0;
    __syncthreads();
    {   // dtype sniff (block-local; ~5 KB L2-broadcast reads)
        if (tid < 128) {
            if (ei[2 * tid + 1] != 0) atomicOr(&s_oddnz, 1);
        }
        const unsigned short* xs = (const unsigned short*)x;
        unsigned short u = xs[tid * 8];
        float f = __uint_as_float(((unsigned int)u) << 16);
        int big = !(fabsf(f) < 64.0f);
        unsigned short u2 = xs[tid * 8 + 5];
        float f2 = __uint_as_float(((unsigned int)u2) << 16);
        big |= !(fabsf(f2) < 64.0f);
        if (big) atomicOr(&s_big, 1);
    }
    __syncthreads();
    int iw = (s_oddnz == 0) ? 1 : 0;   // 1 = int64 edge_index
    int ff = s_big ? 1 : 0;            // 1 = fp32 floats
    if (blockIdx.x == 0 && tid == 0) { flags[0] = iw; flags[1] = ff; }

    // weight conversion (blocks 0..40; 41*256 = 10496 >= 10368)
    if (blockIdx.x < 41) {
        int idx = blockIdx.x * 256 + tid;
        if (idx < 10368) {
            const void* src; long off; int mode; long dst = 0;
            if      (idx < 960)  { src = w1; off = idx;        mode = 0; dst = W1F_O + idx; }
            else if (idx < 1056) { src = b1; off = idx - 960;  mode = 0; dst = B1F_O + (idx - 960); }
            else if (idx < 1104) { src = bm; off = idx - 1056; mode = 0; dst = BMF_O + (idx - 1056); }
            else if (idx < 1152) { src = bl; off = idx - 1104; mode = 0; dst = BLF_O + (idx - 1104); }
            else if (idx < 5760) { src = wm; off = idx - 1152; mode = 1; }
            else                 { src = wl; off = idx - 5760; mode = 2; }
            float v = ff ? ((const float*)src)[off] : b2f(((const bf16*)src)[off]);
            if (mode == 0) F[dst] = v;
            else if (mode == 1) wct[(off % OUTC) * (long)HID + off / OUTC] = f2bu(v);
            else                wct[(OUTC + off % OUTC) * (long)HID + off / OUTC] = f2bu(v);
        }
    }

    // read own edge slice once -> regs (packed row | col<<16)
    unsigned int wreg[16];
    int base = blockIdx.x * 1000;              // groups of 4 edges
    for (int it = 0; it < 4; ++it) {
        int j = it * 256 + tid;
        if (j < 1000) {
            int j4 = base + j;
            int r0, r1, r2, r3, c0, c1, c2, c3;
            if (iw) {
                const int4* pr = (const int4*)ei;
                const int4* pc = (const int4*)(ei + 2L * NED);
                int4 ra = pr[2 * j4], rb = pr[2 * j4 + 1];
                int4 ca = pc[2 * j4], cb = pc[2 * j4 + 1];
                r0 = ra.x; r1 = ra.z; r2 = rb.x; r3 = rb.z;
                c0 = ca.x; c1 = ca.z; c2 = cb.x; c3 = cb.z;
            } else {
                int4 ra = ((const int4*)ei)[j4];
                int4 ca = ((const int4*)(ei + NED))[j4];
                r0 = ra.x; r1 = ra.y; r2 = ra.z; r3 = ra.w;
                c0 = ca.x; c1 = ca.y; c2 = ca.z; c3 = ca.w;
            }
            wreg[4 * it]     = (unsigned)r0 | ((unsigned)c0 << 16);
            wreg[4 * it + 1] = (unsigned)r1 | ((unsigned)c1 << 16);
            wreg[4 * it + 2] = (unsigned)r2 | ((unsigned)c2 << 16);
            wreg[4 * it + 3] = (unsigned)r3 | ((unsigned)c3 << 16);
            atomicAdd(&counts[wreg[4 * it]     >> 25], 1);
            atomicAdd(&counts[wreg[4 * it + 1] >> 25], 1);
            atomicAdd(&counts[wreg[4 * it + 2] >> 25], 1);
            atomicAdd(&counts[wreg[4 * it + 3] >> 25], 1);
        }
    }
    __syncthreads();
    if (tid < NW) {   // tiny serial exclusive scan per thread
        int run = 0;
        for (int j = 0; j < tid; ++j) run += counts[j];
        cur[tid] = run;
        cmat[tid * PB + blockIdx.x] = counts[tid];
        smat[tid * PB + blockIdx.x] = blockIdx.x * PBE + run;
    }
    __syncthreads();
    for (int it = 0; it < 4; ++it) {
        int j = it * 256 + tid;
        if (j < 1000) {
#pragma unroll
            for (int q = 0; q < 4; ++q) {
                unsigned int w = wreg[4 * it + q];
                int pos = atomicAdd(&cur[w >> 25], 1);
                buf[pos] = w;
            }
        }
    }
    __syncthreads();
    for (int i = tid; i < PBE; i += 256) part[blockIdx.x * PBE + i] = buf[i];
}

// K2: window build. Block w reads only its ~200 runs (~33 KB, L2-hot):
// LDS histogram (512 nodes) -> scan -> cnt/start/dis writes + x' = dis*x from
// RAW input x (block-local ff sniff) -> LDS-cursor place of u16 src records
// into the window's PRIVATE 18 KB CSR segment. 16 waves.
__global__ __launch_bounds__(1024) void k_win(const unsigned int* part, const int* smat,
                                              const int* cmat, const void* x, float* F,
                                              int* cnt, int* start, unsigned short* csr) {
    __shared__ int Lrun[PB], Srun[PB];
    __shared__ int hist[SPAN], st[SPAN], cur[SPAN];
    __shared__ float dl[SPAN];
    __shared__ int s_big;
    int tid = threadIdx.x;
    int w = blockIdx.x;
    if (tid == 0) s_big = 0;
    if (tid < PB) { Lrun[tid] = cmat[w * PB + tid]; Srun[tid] = smat[w * PB + tid]; }
    if (tid < SPAN) hist[tid] = 0;
    __syncthreads();
    if (tid < 256) {   // ff sniff
        const unsigned short* xs = (const unsigned short*)x;
        unsigned short u = xs[tid * 8];
        float f = __uint_as_float(((unsigned int)u) << 16);
        int big = !(fabsf(f) < 64.0f);
        unsigned short u2 = xs[tid * 8 + 5];
        float f2 = __uint_as_float(((unsigned int)u2) << 16);
        big |= !(fabsf(f2) < 64.0f);
        if (big) atomicOr(&s_big, 1);
    }
    unsigned int lo = (unsigned)w * SPAN;
    int wave = tid >> 6, lane = tid & 63;
    for (int rb = wave; rb < PB; rb += 16) {
        int L = Lrun[rb], S = Srun[rb];
        for (int i = lane; i < L; i += 64)
            atomicAdd(&hist[(part[S + i] >> 16) - lo], 1);
    }
    __syncthreads();
    int ff = s_big;
    if (tid < SPAN) st[tid] = hist[tid];
    __syncthreads();
    for (int off = 1; off < SPAN; off <<= 1) {
        int t = (tid < SPAN && tid >= off) ? st[tid - off] : 0;
        __syncthreads();
        if (tid < SPAN) st[tid] += t;
        __syncthreads();
    }
    if (tid < SPAN) {
        int h0 = hist[tid];
        int abs0 = w * EW_CAP + (st[tid] - h0);
        cur[tid] = abs0;
        float dis = rsqrtf((float)h0 + 1.0f);
        dl[tid] = dis;
        int g = (int)lo + tid;
        if (g < NND) {
            cnt[g] = h0; start[g] = abs0;
            F[DIS_O + g] = dis;
        }
    }
    __syncthreads();
    // x' = dis * x from raw input (coalesced)
    for (int i = tid; i < SPAN * INC; i += 1024) {
        int node = (int)lo + i / INC;
        if (node < NND) {
            long xo = (long)node * INC + (i % INC);
            float xv = ff ? ((const float*)x)[xo] : b2f(((const bf16*)x)[xo]);
            F[XS_O + xo] = dl[i / INC] * xv;
        }
    }
    int lim = (w + 1) * EW_CAP;
    for (int rb = wave; rb < PB; rb += 16) {
        int L = Lrun[rb], S = Srun[rb];
        for (int i = lane; i < L; i += 64) {
            unsigned int e = part[S + i];
            int pos = atomicAdd(&cur[(e >> 16) - lo], 1);
            if (pos < lim) csr[pos] = (unsigned short)(e & 0xffffu);
        }
    }
}

// K3: fused layer1 — FOUR threads per node (quad in-wave), u16 records,
// x' gather (no per-edge norm), butterfly, scale by dis_c, GEMV via LDS W1,
// write h' = dis_c * relu(...) as packed bf16.
__global__ __launch_bounds__(256) void k_layer1(const int* cnt, const int* start,
                                                const unsigned short* csr, const float* F,
                                                unsigned short* h) {
    __shared__ float w1s[1056];   // W1 (960) then b1 (96), contiguous in F
    for (int i = threadIdx.x; i < 1056; i += 256) w1s[i] = F[W1F_O + i];
    __syncthreads();
    int idx = blockIdx.x * 256 + threadIdx.x;
    if (idx >= NND * 4) return;
    int node = idx >> 2, sub = idx & 3;
    int s = start[node], t = s + cnt[node];
    int lim = ((node >> 9) + 1) * EW_CAP;
    if (t > lim) t = lim;                 // capacity guard
    float ax[INC];
#pragma unroll
    for (int j = 0; j < INC; ++j) ax[j] = 0.0f;
    for (int k = s + sub; k < t; k += 4) {
        int src = csr[k];
        const float2* xr = (const float2*)(F + XS_O + (long)src * INC);
#pragma unroll
        for (int j = 0; j < 5; ++j) {
            float2 v = xr[j];
            ax[2 * j]     += v.x;
            ax[2 * j + 1] += v.y;
        }
    }
    if (sub == 0) {   // self term: + x'_c
        const float2* xr = (const float2*)(F + XS_O + (long)node * INC);
#pragma unroll
        for (int j = 0; j < 5; ++j) {
            float2 v = xr[j];
            ax[2 * j]     += v.x;
            ax[2 * j + 1] += v.y;
        }
    }
    // quad butterfly (quads are wave-aligned: masks 1,2 stay inside the quad)
#pragma unroll
    for (int j = 0; j < INC; ++j) {
        ax[j] += __shfl_xor(ax[j], 1, 64);
        ax[j] += __shfl_xor(ax[j], 2, 64);
    }
    float dn = F[DIS_O + node];
#pragma unroll
    for (int j = 0; j < INC; ++j) ax[j] *= dn;   // agg = dis_c * (sum + self)
    int f0 = sub * 24;
    unsigned int* hrow = (unsigned int*)(h + (size_t)node * HID);
#pragma unroll
    for (int f = f0; f < f0 + 24; f += 2) {
        float a0 = w1s[960 + f], a1 = w1s[960 + f + 1];
#pragma unroll
        for (int kk = 0; kk < INC; ++kk) {
            a0 = fmaf(ax[kk], w1s[kk * HID + f], a0);
            a1 = fmaf(ax[kk], w1s[kk * HID + f + 1], a1);
        }
        a0 = fmaxf(a0, 0.0f) * dn;     // h' = dis_c * relu(...)
        a1 = fmaxf(a1, 0.0f) * dn;
        unsigned int u0 = f2bu(a0), u1 = f2bu(a1);
        hrow[f >> 1] = u0 | (u1 << 16);
    }
}

// K4: gather-aggregate — one wave per node, lanes 0..47 = feature pairs,
// pure-add inner loop over h' (prescaled), final scale by dis_c, v bf16.
__global__ __launch_bounds__(256) void k_gaggh(const int* cnt, const int* start,
                                               const unsigned short* csr, const float* F,
                                               const unsigned short* h, unsigned int* v) {
    int wid = threadIdx.x >> 6;
    int lane = threadIdx.x & 63;
    int node = blockIdx.x * 4 + wid;
    if (lane >= 48) return;
    const unsigned int* hb = (const unsigned int*)h;

    int s = start[node], t = s + cnt[node];
    int lim = ((node >> 9) + 1) * EW_CAP;
    if (t > lim) t = lim;
    float a0 = 0.0f, a1 = 0.0f;
    int k = s;
    for (; k + 7 < t; k += 8) {
        int s0 = csr[k],     s1 = csr[k + 1], s2 = csr[k + 2], s3 = csr[k + 3];
        int s4 = csr[k + 4], s5 = csr[k + 5], s6 = csr[k + 6], s7 = csr[k + 7];
        unsigned int p0 = hb[(size_t)s0 * 48 + lane];
        unsigned int p1 = hb[(size_t)s1 * 48 + lane];
        unsigned int p2 = hb[(size_t)s2 * 48 + lane];
        unsigned int p3 = hb[(size_t)s3 * 48 + lane];
        unsigned int p4 = hb[(size_t)s4 * 48 + lane];
        unsigned int p5 = hb[(size_t)s5 * 48 + lane];
        unsigned int p6 = hb[(size_t)s6 * 48 + lane];
        unsigned int p7 = hb[(size_t)s7 * 48 + lane];
        a0 += bfLo(p0); a1 += bfHi(p0);
        a0 += bfLo(p1); a1 += bfHi(p1);
        a0 += bfLo(p2); a1 += bfHi(p2);
        a0 += bfLo(p3); a1 += bfHi(p3);
        a0 += bfLo(p4); a1 += bfHi(p4);
        a0 += bfLo(p5); a1 += bfHi(p5);
        a0 += bfLo(p6); a1 += bfHi(p6);
        a0 += bfLo(p7); a1 += bfHi(p7);
    }
    for (; k < t; ++k) {
        unsigned int p0 = hb[(size_t)csr[k] * 48 + lane];
        a0 += bfLo(p0); a1 += bfHi(p0);
    }
    unsigned int ps = hb[(size_t)node * 48 + lane];   // + h'_c (self)
    a0 += bfLo(ps); a1 += bfHi(ps);
    float dn = F[DIS_O + node];
    a0 *= dn; a1 *= dn;                                // v = dis_c * (...)
    v[(size_t)node * 48 + lane] = (unsigned int)f2bu(a0) | ((unsigned int)f2bu(a1) << 16);
}

// K5: MFMA head GEMM — v[50000,96]bf16 @ WcatT^T + bias -> d_out.
__global__ __launch_bounds__(256) void k_heads(const unsigned short* v, const unsigned short* wct,
                                               const float* F, const int* flags, void* dout) {
    int wid = threadIdx.x >> 6;
    int lane = threadIdx.x & 63;
    int mtile = blockIdx.x * 4 + wid;
    if (mtile >= MTILES) return;
    int l16 = lane & 15, quad = lane >> 4;

    const unsigned short* vb = v + ((size_t)mtile * 16 + l16) * HID + quad * 8;
    short8 afr0 = *(const short8*)(vb);
    short8 afr1 = *(const short8*)(vb + 32);
    short8 afr2 = *(const short8*)(vb + 64);

    int ff = flags[1];
#pragma unroll
    for (int nt = 0; nt < 6; ++nt) {
        const unsigned short* wb = wct + ((size_t)nt * 16 + l16) * HID + quad * 8;
        short8 b0 = *(const short8*)(wb);
        short8 b1 = *(const short8*)(wb + 32);
        short8 b2 = *(const short8*)(wb + 64);
        f32x4 acc = {0.0f, 0.0f, 0.0f, 0.0f};
        acc = __builtin_amdgcn_mfma_f32_16x16x32_bf16(afr0, b0, acc, 0, 0, 0);
        acc = __builtin_amdgcn_mfma_f32_16x16x32_bf16(afr1, b1, acc, 0, 0, 0);
        acc = __builtin_amdgcn_mfma_f32_16x16x32_bf16(afr2, b2, acc, 0, 0, 0);
        int n = nt * 16 + l16;                 // 0..95: <48 mu, >=48 logstd
        float bias = (n < OUTC) ? F[BMF_O + n] : F[BLF_O + n - OUTC];
        long obase = (n < OUTC) ? ((long)n) : (NOUT + (long)(n - OUTC));
#pragma unroll
        for (int r = 0; r < 4; ++r) {
            int m = mtile * 16 + quad * 4 + r;
            float val = acc[r] + bias;
            long oi = (long)m * OUTC + obase;
            if (ff) ((float*)dout)[oi] = val;
            else    ((bf16*)dout)[oi] = __float2bfloat16(val);
        }
    }
}

extern "C" void kernel_launch(void* const* d_in, const int* in_sizes, int n_in,
                              void* d_out, int out_size, void* d_ws, size_t ws_size,
                              hipStream_t stream) {
    const int* ei = (const int*)d_in[1];
    int* flags = (int*)d_ws;
    float* F = (float*)((char*)d_ws + 256);
    unsigned short* h   = (unsigned short*)(F + FLOATS_TOT);
    unsigned short* wct = h + (size_t)NND * HID;
    unsigned short* vv  = wct + (size_t)HID * HID;
    int* cnt   = (int*)(vv + (size_t)NND * HID);
    int* start = cnt + NND;
    unsigned int* part = (unsigned int*)(start + NND);
    int* smat = (int*)(part + NED);
    int* cmat = smat + NW * PB;
    unsigned short* csr = (unsigned short*)(cmat + NW * PB);

    k_part<<<PB, 256, 0, stream>>>(ei, d_in[0], d_in[2], d_in[3], d_in[4],
                                   d_in[5], d_in[6], d_in[7], flags, F, wct,
                                   part, smat, cmat);
    k_win<<<NW, 1024, 0, stream>>>(part, smat, cmat, d_in[0], F, cnt, start, csr);
    k_layer1<<<(NND * 4 + 255) / 256, 256, 0, stream>>>(cnt, start, csr, F, h);
    k_gaggh<<<NND / 4, 256, 0, stream>>>(cnt, start, csr, F, h, (unsigned int*)vv);
    k_heads<<<(MTILES + 3) / 4, 256, 0, stream>>>(vv, wct, F, flags, d_out);
}

// Round 13
// 149.408 us; speedup vs baseline: 5.7603x; 1.1162x over previous
//
#include <hip/hip_runtime.h>
#include <hip/hip_bf16.h>

// Problem constants
#define NND 50000      // nodes
#define NED 800000     // edges (without self-loops)
#define INC 10
#define HID 96
#define OUTC 48
#define NOUT (NND*OUTC)
#define MTILES 3125    // 50000 / 16
#define NW 98          // dest windows of SPAN nodes
#define SPAN 512
#define EW_CAP 9216    // CSR capacity per window (Poisson 8163 + 11 sigma)
#define PB 200         // partition blocks
#define PBE 4000       // edges per partition block (200*4000 = 800000 exact)

typedef __hip_bfloat16 bf16;
typedef __attribute__((ext_vector_type(8))) short short8;
typedef __attribute__((ext_vector_type(4))) float f32x4;

// ---- workspace layout ----
// header ints: [0..1] flags (k_part block 0). 256B reserved.
// F floats (from d_ws+256):
#define W1F_O  0L                 // 960 (W1 then b1: 1056 contiguous)
#define B1F_O  960L               // 96
#define BMF_O  1056L              // 48
#define BLF_O  1104L              // 48
#define DIS_O  1152L              // 50000 rsqrt(deg+1)   (k_win)
#define XS_O   51152L             // 500000 x' = dis*x    (k_win, fp32)
#define FLOATS_TOT 551152L
// then: h' [NND*96] bf16 (dis-prescaled hidden), wct [96*96] bf16
// then ints: cnt[50000], start[50000], part[800000], smat[NW*PB], cmat[NW*PB];
// then csr u16 [NW*EW_CAP]

__device__ __forceinline__ float b2f(bf16 v) { return __bfloat162float(v); }
__device__ __forceinline__ float bfLo(unsigned int p) { return __uint_as_float(p << 16); }
__device__ __forceinline__ float bfHi(unsigned int p) { return __uint_as_float(p & 0xffff0000u); }
__device__ __forceinline__ unsigned short f2bu(float v) {
    return __bfloat16_as_ushort(__float2bfloat16(v));
}

// K1: partition + weights. Block b owns edges [b*4000,+4000): block-local sniff,
// read edge slice ONCE into registers, LDS histogram by dest window (c>>9),
// LDS scan, LDS place, coalesced 16 KB run write + run matrix. Blocks 0..40
// also convert the 10368 weight/bias elements. No global atomics.
__global__ __launch_bounds__(256) void k_part(const int* ei, const void* x,
                                              const void* w1, const void* b1,
                                              const void* wm, const void* bm,
                                              const void* wl, const void* bl,
                                              int* flags, float* F, unsigned short* wct,
                                              unsigned int* part, int* smat, int* cmat) {
    __shared__ int s_oddnz, s_big;
    __shared__ int counts[NW], cur[NW];
    __shared__ unsigned int buf[PBE];
    int tid = threadIdx.x;
    if (tid == 0) { s_oddnz = 0; s_big = 0; }
    for (int i = tid; i < NW; i += 256) counts[i] = 0;
    __syncthreads();
    {   // dtype sniff (block-local; ~5 KB L2-broadcast reads)
        if (tid < 128) {
            if (ei[2 * tid + 1] != 0) atomicOr(&s_oddnz, 1);
        }
        const unsigned short* xs = (const unsigned short*)x;
        unsigned short u = xs[tid * 8];
        float f = __uint_as_float(((unsigned int)u) << 16);
        int big = !(fabsf(f) < 64.0f);
        unsigned short u2 = xs[tid * 8 + 5];
        float f2 = __uint_as_float(((unsigned int)u2) << 16);
        big |= !(fabsf(f2) < 64.0f);
        if (big) atomicOr(&s_big, 1);
    }
    __syncthreads();
    int iw = (s_oddnz == 0) ? 1 : 0;   // 1 = int64 edge_index
    int ff = s_big ? 1 : 0;            // 1 = fp32 floats
    if (blockIdx.x == 0 && tid == 0) { flags[0] = iw; flags[1] = ff; }

    // weight conversion (blocks 0..40; 41*256 = 10496 >= 10368)
    if (blockIdx.x < 41) {
        int idx = blockIdx.x * 256 + tid;
        if (idx < 10368) {
            const void* src; long off; int mode; long dst = 0;
            if      (idx < 960)  { src = w1; off = idx;        mode = 0; dst = W1F_O + idx; }
            else if (idx < 1056) { src = b1; off = idx - 960;  mode = 0; dst = B1F_O + (idx - 960); }
            else if (idx < 1104) { src = bm; off = idx - 1056; mode = 0; dst = BMF_O + (idx - 1056); }
            else if (idx < 1152) { src = bl; off = idx - 1104; mode = 0; dst = BLF_O + (idx - 1104); }
            else if (idx < 5760) { src = wm; off = idx - 1152; mode = 1; }
            else                 { src = wl; off = idx - 5760; mode = 2; }
            float v = ff ? ((const float*)src)[off] : b2f(((const bf16*)src)[off]);
            if (mode == 0) F[dst] = v;
            else if (mode == 1) wct[(off % OUTC) * (long)HID + off / OUTC] = f2bu(v);
            else                wct[(OUTC + off % OUTC) * (long)HID + off / OUTC] = f2bu(v);
        }
    }

    // read own edge slice once -> regs (packed row | col<<16)
    unsigned int wreg[16];
    int base = blockIdx.x * 1000;              // groups of 4 edges
    for (int it = 0; it < 4; ++it) {
        int j = it * 256 + tid;
        if (j < 1000) {
            int j4 = base + j;
            int r0, r1, r2, r3, c0, c1, c2, c3;
            if (iw) {
                const int4* pr = (const int4*)ei;
                const int4* pc = (const int4*)(ei + 2L * NED);
                int4 ra = pr[2 * j4], rb = pr[2 * j4 + 1];
                int4 ca = pc[2 * j4], cb = pc[2 * j4 + 1];
                r0 = ra.x; r1 = ra.z; r2 = rb.x; r3 = rb.z;
                c0 = ca.x; c1 = ca.z; c2 = cb.x; c3 = cb.z;
            } else {
                int4 ra = ((const int4*)ei)[j4];
                int4 ca = ((const int4*)(ei + NED))[j4];
                r0 = ra.x; r1 = ra.y; r2 = ra.z; r3 = ra.w;
                c0 = ca.x; c1 = ca.y; c2 = ca.z; c3 = ca.w;
            }
            wreg[4 * it]     = (unsigned)r0 | ((unsigned)c0 << 16);
            wreg[4 * it + 1] = (unsigned)r1 | ((unsigned)c1 << 16);
            wreg[4 * it + 2] = (unsigned)r2 | ((unsigned)c2 << 16);
            wreg[4 * it + 3] = (unsigned)r3 | ((unsigned)c3 << 16);
            atomicAdd(&counts[wreg[4 * it]     >> 25], 1);
            atomicAdd(&counts[wreg[4 * it + 1] >> 25], 1);
            atomicAdd(&counts[wreg[4 * it + 2] >> 25], 1);
            atomicAdd(&counts[wreg[4 * it + 3] >> 25], 1);
        }
    }
    __syncthreads();
    if (tid < NW) {   // tiny serial exclusive scan per thread
        int run = 0;
        for (int j = 0; j < tid; ++j) run += counts[j];
        cur[tid] = run;
        cmat[tid * PB + blockIdx.x] = counts[tid];
        smat[tid * PB + blockIdx.x] = blockIdx.x * PBE + run;
    }
    __syncthreads();
    for (int it = 0; it < 4; ++it) {
        int j = it * 256 + tid;
        if (j < 1000) {
#pragma unroll
            for (int q = 0; q < 4; ++q) {
                unsigned int w = wreg[4 * it + q];
                int pos = atomicAdd(&cur[w >> 25], 1);
                buf[pos] = w;
            }
        }
    }
    __syncthreads();
    for (int i = tid; i < PBE; i += 256) part[blockIdx.x * PBE + i] = buf[i];
}

// K2: window build. Block w reads only its ~200 runs (~33 KB, L2-hot):
// LDS histogram (512 nodes) -> scan -> cnt/start/dis writes + x' = dis*x from
// RAW input x -> LDS-cursor place of u16 src records into the window's
// PRIVATE 18 KB CSR segment. 16 waves.
__global__ __launch_bounds__(1024) void k_win(const unsigned int* part, const int* smat,
                                              const int* cmat, const void* x, float* F,
                                              int* cnt, int* start, unsigned short* csr) {
    __shared__ int Lrun[PB], Srun[PB];
    __shared__ int hist[SPAN], st[SPAN], cur[SPAN];
    __shared__ float dl[SPAN];
    __shared__ int s_big;
    int tid = threadIdx.x;
    int w = blockIdx.x;
    if (tid == 0) s_big = 0;
    if (tid < PB) { Lrun[tid] = cmat[w * PB + tid]; Srun[tid] = smat[w * PB + tid]; }
    if (tid < SPAN) hist[tid] = 0;
    __syncthreads();
    if (tid < 256) {   // ff sniff
        const unsigned short* xs = (const unsigned short*)x;
        unsigned short u = xs[tid * 8];
        float f = __uint_as_float(((unsigned int)u) << 16);
        int big = !(fabsf(f) < 64.0f);
        unsigned short u2 = xs[tid * 8 + 5];
        float f2 = __uint_as_float(((unsigned int)u2) << 16);
        big |= !(fabsf(f2) < 64.0f);
        if (big) atomicOr(&s_big, 1);
    }
    unsigned int lo = (unsigned)w * SPAN;
    int wave = tid >> 6, lane = tid & 63;
    for (int rb = wave; rb < PB; rb += 16) {
        int L = Lrun[rb], S = Srun[rb];
        for (int i = lane; i < L; i += 64)
            atomicAdd(&hist[(part[S + i] >> 16) - lo], 1);
    }
    __syncthreads();
    int ff = s_big;
    if (tid < SPAN) st[tid] = hist[tid];
    __syncthreads();
    for (int off = 1; off < SPAN; off <<= 1) {
        int t = (tid < SPAN && tid >= off) ? st[tid - off] : 0;
        __syncthreads();
        if (tid < SPAN) st[tid] += t;
        __syncthreads();
    }
    if (tid < SPAN) {
        int h0 = hist[tid];
        int abs0 = w * EW_CAP + (st[tid] - h0);
        cur[tid] = abs0;
        float dis = rsqrtf((float)h0 + 1.0f);
        dl[tid] = dis;
        int g = (int)lo + tid;
        if (g < NND) {
            cnt[g] = h0; start[g] = abs0;
            F[DIS_O + g] = dis;
        }
    }
    __syncthreads();
    // x' = dis * x from raw input (coalesced)
    for (int i = tid; i < SPAN * INC; i += 1024) {
        int node = (int)lo + i / INC;
        if (node < NND) {
            long xo = (long)node * INC + (i % INC);
            float xv = ff ? ((const float*)x)[xo] : b2f(((const bf16*)x)[xo]);
            F[XS_O + xo] = dl[i / INC] * xv;
        }
    }
    int lim = (w + 1) * EW_CAP;
    for (int rb = wave; rb < PB; rb += 16) {
        int L = Lrun[rb], S = Srun[rb];
        for (int i = lane; i < L; i += 64) {
            unsigned int e = part[S + i];
            int pos = atomicAdd(&cur[(e >> 16) - lo], 1);
            if (pos < lim) csr[pos] = (unsigned short)(e & 0xffffu);
        }
    }
}

// K3: fused layer1 — FOUR threads per node (quad in-wave), u16 records,
// x' gather, butterfly, scale by dis_c, GEMV via LDS W1,
// write h' = dis_c * relu(...) as packed bf16.
__global__ __launch_bounds__(256) void k_layer1(const int* cnt, const int* start,
                                                const unsigned short* csr, const float* F,
                                                unsigned short* h) {
    __shared__ float w1s[1056];   // W1 (960) then b1 (96), contiguous in F
    for (int i = threadIdx.x; i < 1056; i += 256) w1s[i] = F[W1F_O + i];
    __syncthreads();
    int idx = blockIdx.x * 256 + threadIdx.x;
    if (idx >= NND * 4) return;
    int node = idx >> 2, sub = idx & 3;
    int s = start[node], t = s + cnt[node];
    int lim = ((node >> 9) + 1) * EW_CAP;
    if (t > lim) t = lim;                 // capacity guard
    float ax[INC];
#pragma unroll
    for (int j = 0; j < INC; ++j) ax[j] = 0.0f;
    for (int k = s + sub; k < t; k += 4) {
        int src = csr[k];
        const float2* xr = (const float2*)(F + XS_O + (long)src * INC);
#pragma unroll
        for (int j = 0; j < 5; ++j) {
            float2 v = xr[j];
            ax[2 * j]     += v.x;
            ax[2 * j + 1] += v.y;
        }
    }
    if (sub == 0) {   // self term: + x'_c
        const float2* xr = (const float2*)(F + XS_O + (long)node * INC);
#pragma unroll
        for (int j = 0; j < 5; ++j) {
            float2 v = xr[j];
            ax[2 * j]     += v.x;
            ax[2 * j + 1] += v.y;
        }
    }
    // quad butterfly (quads are wave-aligned: masks 1,2 stay inside the quad)
#pragma unroll
    for (int j = 0; j < INC; ++j) {
        ax[j] += __shfl_xor(ax[j], 1, 64);
        ax[j] += __shfl_xor(ax[j], 2, 64);
    }
    float dn = F[DIS_O + node];
#pragma unroll
    for (int j = 0; j < INC; ++j) ax[j] *= dn;   // agg = dis_c * (sum + self)
    int f0 = sub * 24;
    unsigned int* hrow = (unsigned int*)(h + (size_t)node * HID);
#pragma unroll
    for (int f = f0; f < f0 + 24; f += 2) {
        float a0 = w1s[960 + f], a1 = w1s[960 + f + 1];
#pragma unroll
        for (int kk = 0; kk < INC; ++kk) {
            a0 = fmaf(ax[kk], w1s[kk * HID + f], a0);
            a1 = fmaf(ax[kk], w1s[kk * HID + f + 1], a1);
        }
        a0 = fmaxf(a0, 0.0f) * dn;     // h' = dis_c * relu(...)
        a1 = fmaxf(a1, 0.0f) * dn;
        unsigned int u0 = f2bu(a0), u1 = f2bu(a1);
        hrow[f >> 1] = u0 | (u1 << 16);
    }
}

// K4: fused gather + MFMA heads. One wave per 16-node M-tile. Lane (l16,quad)
// accumulates feats k = g*32 + quad*8 + j of node l16 directly in A-fragment
// layout (24 fp32). Per edge the 4 quads read the 192B h'-row as 3 disjoint
// 64B-aligned uint4 chunks (row read exactly once; all 64 lanes active).
// Then v-frags (bf16, same rounding as before) -> 18 MFMA -> bias -> store.
__global__ __launch_bounds__(256) void k_gh(const int* cnt, const int* start,
                                            const unsigned short* csr, const float* F,
                                            const unsigned short* h, const unsigned short* wct,
                                            const int* flags, void* dout) {
    int wid = threadIdx.x >> 6;
    int lane = threadIdx.x & 63;
    int mtile = blockIdx.x * 4 + wid;
    if (mtile >= MTILES) return;
    int l16 = lane & 15, quad = lane >> 4;
    int node = mtile * 16 + l16;

    const uint4* hb4 = (const uint4*)h;   // h row = 12 uint4 (192 B, 64B-aligned)
    long rowq = (long)node * 12;

    int s = start[node], c = cnt[node];
    int lim = ((node >> 9) + 1) * EW_CAP;
    if (s + c > lim) c = lim - s;

    float acc[3][8];
    // self term: + h'_node
    {
        uint4 p0 = hb4[rowq + quad];
        uint4 p1 = hb4[rowq + 4 + quad];
        uint4 p2 = hb4[rowq + 8 + quad];
#pragma unroll
        for (int t = 0; t < 4; ++t) {
            unsigned int w0 = (t == 0) ? p0.x : (t == 1) ? p0.y : (t == 2) ? p0.z : p0.w;
            unsigned int w1 = (t == 0) ? p1.x : (t == 1) ? p1.y : (t == 2) ? p1.z : p1.w;
            unsigned int w2 = (t == 0) ? p2.x : (t == 1) ? p2.y : (t == 2) ? p2.z : p2.w;
            acc[0][2 * t] = bfLo(w0); acc[0][2 * t + 1] = bfHi(w0);
            acc[1][2 * t] = bfLo(w1); acc[1][2 * t + 1] = bfHi(w1);
            acc[2][2 * t] = bfLo(w2); acc[2][2 * t + 1] = bfHi(w2);
        }
    }
    // edge loop (per-lane length; exec-mask divergence within the tile)
    int k = 0;
    for (; k + 1 < c; k += 2) {
        int s0 = csr[s + k], s1 = csr[s + k + 1];
        long r0 = (long)s0 * 12, r1 = (long)s1 * 12;
        uint4 a0 = hb4[r0 + quad], a1 = hb4[r0 + 4 + quad], a2 = hb4[r0 + 8 + quad];
        uint4 b0 = hb4[r1 + quad], b1 = hb4[r1 + 4 + quad], b2 = hb4[r1 + 8 + quad];
#pragma unroll
        for (int t = 0; t < 4; ++t) {
            unsigned int w0 = (t == 0) ? a0.x : (t == 1) ? a0.y : (t == 2) ? a0.z : a0.w;
            unsigned int w1 = (t == 0) ? a1.x : (t == 1) ? a1.y : (t == 2) ? a1.z : a1.w;
            unsigned int w2 = (t == 0) ? a2.x : (t == 1) ? a2.y : (t == 2) ? a2.z : a2.w;
            acc[0][2 * t] += bfLo(w0); acc[0][2 * t + 1] += bfHi(w0);
            acc[1][2 * t] += bfLo(w1); acc[1][2 * t + 1] += bfHi(w1);
            acc[2][2 * t] += bfLo(w2); acc[2][2 * t + 1] += bfHi(w2);
        }
#pragma unroll
        for (int t = 0; t < 4; ++t) {
            unsigned int w0 = (t == 0) ? b0.x : (t == 1) ? b0.y : (t == 2) ? b0.z : b0.w;
            unsigned int w1 = (t == 0) ? b1.x : (t == 1) ? b1.y : (t == 2) ? b1.z : b1.w;
            unsigned int w2 = (t == 0) ? b2.x : (t == 1) ? b2.y : (t == 2) ? b2.z : b2.w;
            acc[0][2 * t] += bfLo(w0); acc[0][2 * t + 1] += bfHi(w0);
            acc[1][2 * t] += bfLo(w1); acc[1][2 * t + 1] += bfHi(w1);
            acc[2][2 * t] += bfLo(w2); acc[2][2 * t + 1] += bfHi(w2);
        }
    }
    if (k < c) {
        int s0 = csr[s + k];
        long r0 = (long)s0 * 12;
        uint4 a0 = hb4[r0 + quad], a1 = hb4[r0 + 4 + quad], a2 = hb4[r0 + 8 + quad];
#pragma unroll
        for (int t = 0; t < 4; ++t) {
            unsigned int w0 = (t == 0) ? a0.x : (t == 1) ? a0.y : (t == 2) ? a0.z : a0.w;
            unsigned int w1 = (t == 0) ? a1.x : (t == 1) ? a1.y : (t == 2) ? a1.z : a1.w;
            unsigned int w2 = (t == 0) ? a2.x : (t == 1) ? a2.y : (t == 2) ? a2.z : a2.w;
            acc[0][2 * t] += bfLo(w0); acc[0][2 * t + 1] += bfHi(w0);
            acc[1][2 * t] += bfLo(w1); acc[1][2 * t + 1] += bfHi(w1);
            acc[2][2 * t] += bfLo(w2); acc[2][2 * t + 1] += bfHi(w2);
        }
    }
    // v = dis_c * (...)  -> bf16 A-frags (identical rounding to old v store)
    float dn = F[DIS_O + node];
    short8 af[3];
#pragma unroll
    for (int g = 0; g < 3; ++g)
#pragma unroll
        for (int j = 0; j < 8; ++j)
            af[g][j] = (short)f2bu(acc[g][j] * dn);

    int ff = flags[1];
#pragma unroll
    for (int nt = 0; nt < 6; ++nt) {
        const unsigned short* wb = wct + ((size_t)nt * 16 + l16) * HID + quad * 8;
        short8 b0 = *(const short8*)(wb);
        short8 b1 = *(const short8*)(wb + 32);
        short8 b2 = *(const short8*)(wb + 64);
        f32x4 cacc = {0.0f, 0.0f, 0.0f, 0.0f};
        cacc = __builtin_amdgcn_mfma_f32_16x16x32_bf16(af[0], b0, cacc, 0, 0, 0);
        cacc = __builtin_amdgcn_mfma_f32_16x16x32_bf16(af[1], b1, cacc, 0, 0, 0);
        cacc = __builtin_amdgcn_mfma_f32_16x16x32_bf16(af[2], b2, cacc, 0, 0, 0);
        int n = nt * 16 + l16;                 // 0..95: <48 mu, >=48 logstd
        float bias = (n < OUTC) ? F[BMF_O + n] : F[BLF_O + n - OUTC];
        long obase = (n < OUTC) ? ((long)n) : (NOUT + (long)(n - OUTC));
#pragma unroll
        for (int r = 0; r < 4; ++r) {
            int m = mtile * 16 + quad * 4 + r;
            float val = cacc[r] + bias;
            long oi = (long)m * OUTC + obase;
            if (ff) ((float*)dout)[oi] = val;
            else    ((bf16*)dout)[oi] = __float2bfloat16(val);
        }
    }
}

extern "C" void kernel_launch(void* const* d_in, const int* in_sizes, int n_in,
                              void* d_out, int out_size, void* d_ws, size_t ws_size,
                              hipStream_t stream) {
    const int* ei = (const int*)d_in[1];
    int* flags = (int*)d_ws;
    float* F = (float*)((char*)d_ws + 256);
    unsigned short* h   = (unsigned short*)(F + FLOATS_TOT);
    unsigned short* wct = h + (size_t)NND * HID;
    int* cnt   = (int*)(wct + (size_t)HID * HID);
    int* start = cnt + NND;
    unsigned int* part = (unsigned int*)(start + NND);
    int* smat = (int*)(part + NED);
    int* cmat = smat + NW * PB;
    unsigned short* csr = (unsigned short*)(cmat + NW * PB);

    k_part<<<PB, 256, 0, stream>>>(ei, d_in[0], d_in[2], d_in[3], d_in[4],
                                   d_in[5], d_in[6], d_in[7], flags, F, wct,
                                   part, smat, cmat);
    k_win<<<NW, 1024, 0, stream>>>(part, smat, cmat, d_in[0], F, cnt, start, csr);
    k_layer1<<<(NND * 4 + 255) / 256, 256, 0, stream>>>(cnt, start, csr, F, h);
    k_gh<<<(MTILES + 3) / 4, 256, 0, stream>>>(cnt, start, csr, F, h, wct, flags, d_out);
}